// Round 4
// baseline (554.009 us; speedup 1.0000x reference)
//
#include <hip/hip_runtime.h>
#include <math.h>

#define BATCH 8
#define CH    256
#define NPIX  4096
#define CKDIM 64

typedef __attribute__((ext_vector_type(8))) short short8;   // 8 bf16 (4 VGPRs)
typedef __attribute__((ext_vector_type(4))) float f32x4;    // MFMA accumulator

#define MFMA16x16(a, b, c) __builtin_amdgcn_mfma_f32_16x16x32_bf16((a), (b), (c), 0, 0, 0)

__device__ __forceinline__ unsigned short f2bf(float f) {
    union { float f; unsigned int u; } v; v.f = f;
    unsigned int u = v.u;
    u += 0x7fffu + ((u >> 16) & 1u);      // round-to-nearest-even
    return (unsigned short)(u >> 16);
}

// ---------------------------------------------------------------------------
// Kernel P: build W_all[384][256] bf16 (rows: 0-63 wq, 64-127 wk, 128-383 wg@wv)
// and bias_all[384] fp32. grid 384 x 256 threads.
// ---------------------------------------------------------------------------
__global__ void prep_kernel(const float* __restrict__ wq, const float* __restrict__ bq,
                            const float* __restrict__ wk, const float* __restrict__ bk,
                            const float* __restrict__ wv, const float* __restrict__ bv,
                            const float* __restrict__ wg,
                            unsigned short* __restrict__ W_all, float* __restrict__ bias_all) {
    int o = blockIdx.x;
    int c = threadIdx.x;
    if (o < 64) {
        W_all[o * CH + c] = f2bf(wq[o * CH + c]);
        if (c == 0) bias_all[o] = bq[o];
    } else if (o < 128) {
        int oo = o - 64;
        W_all[o * CH + c] = f2bf(wk[oo * CH + c]);
        if (c == 0) bias_all[o] = bk[oo];
    } else {
        int oo = o - 128;
        float acc = 0.f;
        for (int m = 0; m < CH; ++m)
            acc += wg[oo * CH + m] * wv[m * CH + c];
        W_all[o * CH + c] = f2bf(acc);
        if (c == 0) {
            float b = 0.f;
            for (int m = 0; m < CH; ++m) b += wg[oo * CH + m] * bv[m];
            bias_all[o] = b;
        }
    }
}

// ---------------------------------------------------------------------------
// Kernel T: transpose+convert x[b][c][n] fp32 -> xt[b][n][c] bf16.
// 64x64 tiles, 256 threads. LDS stride 65 (<=2-way banks). grid (64, 4, 8).
// ---------------------------------------------------------------------------
__global__ void xpose_kernel(const float* __restrict__ x, unsigned short* __restrict__ xt) {
    __shared__ float Tl[64][65];   // [n][c]
    int n0 = blockIdx.x * 64;
    int c0 = blockIdx.y * 64;
    int b  = blockIdx.z;
    int tid = threadIdx.x;

#pragma unroll
    for (int r = 0; r < 4; ++r) {
        int f  = r * 256 + tid;
        int c  = f >> 4;
        int n4 = f & 15;
        float4 v = *(const float4*)(x + ((size_t)b * CH + c0 + c) * NPIX + n0 + n4 * 4);
        Tl[n4 * 4 + 0][c] = v.x;
        Tl[n4 * 4 + 1][c] = v.y;
        Tl[n4 * 4 + 2][c] = v.z;
        Tl[n4 * 4 + 3][c] = v.w;
    }
    __syncthreads();
#pragma unroll
    for (int r = 0; r < 2; ++r) {
        int f    = r * 256 + tid;
        int nrow = f >> 3;
        int c8   = f & 7;
        unsigned int pk[4];
#pragma unroll
        for (int p = 0; p < 4; ++p) {
            unsigned int lo = f2bf(Tl[nrow][c8 * 8 + p * 2 + 0]);
            unsigned int hi = f2bf(Tl[nrow][c8 * 8 + p * 2 + 1]);
            pk[p] = lo | (hi << 16);
        }
        *(uint4*)(xt + ((size_t)b * NPIX + n0 + nrow) * CH + c0 + c8 * 8) = *(uint4*)pk;
    }
}

// ---------------------------------------------------------------------------
// Kernel G: all-global MFMA GEMM. y[o][n] = sum_c W_all[o][c] xt[n][c] + bias.
// o<128 -> qk[b][n][128] transposed; o>=128 -> vp[b][o-128][n].
// grid (64, 6, 8), 256 threads (4 waves). No LDS.
// ---------------------------------------------------------------------------
__global__ void qkv_mfma(const unsigned short* __restrict__ xt,
                         const unsigned short* __restrict__ W_all,
                         const float* __restrict__ bias_all,
                         unsigned short* __restrict__ qk, unsigned short* __restrict__ vp) {
    int n0   = blockIdx.x * 64;
    int o0   = blockIdx.y * 64;
    int b    = blockIdx.z;
    int lane = threadIdx.x & 63;
    int w    = threadIdx.x >> 6;
    int col  = lane & 15;
    int quad = lane >> 4;

    const unsigned short* Arow = W_all + (size_t)(o0 + w * 16 + col) * CH + quad * 8;

    f32x4 acc[4];
#pragma unroll
    for (int t = 0; t < 4; ++t) acc[t] = (f32x4){0.f, 0.f, 0.f, 0.f};

#pragma unroll
    for (int kc = 0; kc < 8; ++kc) {
        short8 a = *(const short8*)(Arow + kc * 32);
#pragma unroll
        for (int nt = 0; nt < 4; ++nt) {
            short8 bb = *(const short8*)(xt + ((size_t)b * NPIX + n0 + nt * 16 + col) * CH + kc * 32 + quad * 8);
            acc[nt] = MFMA16x16(a, bb, acc[nt]);
        }
    }

    float4 bias = *(const float4*)(bias_all + o0 + w * 16 + quad * 4);
    float bs[4] = {bias.x, bias.y, bias.z, bias.w};

    if (o0 < 128) {
#pragma unroll
        for (int nt = 0; nt < 4; ++nt) {
            int n = n0 + nt * 16 + col;
            unsigned int pk[2];
#pragma unroll
            for (int p = 0; p < 2; ++p) {
                unsigned int lo = f2bf(acc[nt][p * 2 + 0] + bs[p * 2 + 0]);
                unsigned int hi = f2bf(acc[nt][p * 2 + 1] + bs[p * 2 + 1]);
                pk[p] = lo | (hi << 16);
            }
            *(uint2*)(qk + ((size_t)b * NPIX + n) * 128 + o0 + w * 16 + quad * 4) = *(uint2*)pk;
        }
    } else {
#pragma unroll
        for (int nt = 0; nt < 4; ++nt) {
            int n = n0 + nt * 16 + col;
#pragma unroll
            for (int r = 0; r < 4; ++r) {
                int oo = o0 - 128 + w * 16 + quad * 4 + r;
                vp[((size_t)b * CH + oo) * NPIX + n] = f2bf(acc[nt][r] + bs[r]);
            }
        }
    }
}

// ---------------------------------------------------------------------------
// Kernel I: out[b][o][j] = bg[o]  (bias init; attn halves atomically add)
// grid 8192 x 256, float4 stores.
// ---------------------------------------------------------------------------
__global__ void init_out(const float* __restrict__ bg, float* __restrict__ out) {
    int gid = blockIdx.x * 256 + threadIdx.x;   // float4 index
    int o = (gid >> 10) & 255;                  // 1024 float4 per channel row
    float v = bg[o];
    ((float4*)out)[gid] = (float4){v, v, v, v};
}

// ---------------------------------------------------------------------------
// Kernel A: attention, i-split x2. j-tile 128, i-tile 64, 8 waves.
// K-frags hoisted to registers (iter-invariant). Q/V prefetched from global.
// St double-buffered -> ONE barrier per iter. grid 512 (2 blocks/CU):
// id%8 = batch -> each XCD holds one batch's qk+vp (3 MB) in its L2.
// Partial sums atomically added into bias-initialized out.
// ---------------------------------------------------------------------------
#define LPK 72
__global__ __launch_bounds__(512, 4)
void attn_v3(const unsigned short* __restrict__ qk,   // [B][N][128]: q=0..63, k=64..127
             const unsigned short* __restrict__ vp,   // [B][256][N]
             float* __restrict__ out) {
    __shared__ __align__(16) unsigned short St[2][128][LPK];  // 36 KB

    int id    = blockIdx.x;
    int b     = id & 7;             // XCD-local batch
    int jblk  = (id >> 3) & 31;
    int ihalf = id >> 8;            // 0 or 1
    int j0    = jblk * 128;
    int ibase = ihalf * 2048;

    int tid  = threadIdx.x;
    int lane = tid & 63;
    int w    = tid >> 6;
    int col  = lane & 15;
    int quad = lane >> 4;

    int tiB = (w >> 2) * 2;         // phase-A i-subtile pair
    int tjA = (w & 3) * 2;          // phase-A j-tile pair
    int wo  = w >> 1;               // phase-B o 64-block
    int wjB = w & 1;                // phase-B j 64-half

    // iter-invariant K fragments (global, once)
    short8 bK[2][2];
#pragma unroll
    for (int t2 = 0; t2 < 2; ++t2)
#pragma unroll
        for (int ks = 0; ks < 2; ++ks)
            bK[t2][ks] = *(const short8*)(qk + ((size_t)b * NPIX + j0 + (tjA + t2) * 16 + col) * 128 + 64 + ks * 32 + quad * 8);

    // prefetch Q / V fragments for ilocal = 0
    uint4 aQ[2][2];
#pragma unroll
    for (int t = 0; t < 2; ++t)
#pragma unroll
        for (int ks = 0; ks < 2; ++ks)
            aQ[t][ks] = *(const uint4*)(qk + ((size_t)b * NPIX + ibase + (tiB + t) * 16 + col) * 128 + ks * 32 + quad * 8);
    uint4 aV[4][2];
#pragma unroll
    for (int ot = 0; ot < 4; ++ot)
#pragma unroll
        for (int ks = 0; ks < 2; ++ks)
            aV[ot][ks] = *(const uint4*)(vp + ((size_t)b * CH + wo * 64 + ot * 16 + col) * NPIX + ibase + ks * 32 + quad * 8);

    f32x4 acc[4][4];
#pragma unroll
    for (int ot = 0; ot < 4; ++ot)
#pragma unroll
        for (int tj = 0; tj < 4; ++tj) acc[ot][tj] = (f32x4){0.f, 0.f, 0.f, 0.f};

    int p = 0;
    for (int il = 0; il < 2048; il += 64) {
        int inext = ibase + ((il + 64) & 2047);

        // ---- phase A: S[64x128] = Q.K^T, elu/N -> St[p] ----
#pragma unroll
        for (int t = 0; t < 2; ++t) {
#pragma unroll
            for (int t2 = 0; t2 < 2; ++t2) {
                f32x4 s = (f32x4){0.f, 0.f, 0.f, 0.f};
                s = MFMA16x16(*(const short8*)&aQ[t][0], bK[t2][0], s);
                s = MFMA16x16(*(const short8*)&aQ[t][1], bK[t2][1], s);
                unsigned int pk[2];
#pragma unroll
                for (int pp = 0; pp < 2; ++pp) {
                    float e0 = s[pp * 2 + 0];
                    float e1 = s[pp * 2 + 1];
                    e0 = (e0 > 0.f) ? e0 : (__expf(e0) - 1.f);
                    e1 = (e1 > 0.f) ? e1 : (__expf(e1) - 1.f);
                    e0 *= (1.f / (float)NPIX);
                    e1 *= (1.f / (float)NPIX);
                    pk[pp] = (unsigned int)f2bf(e0) | ((unsigned int)f2bf(e1) << 16);
                }
                *(uint2*)&St[p][(tjA + t2) * 16 + col][(tiB + t) * 16 + quad * 4] = *(uint2*)pk;
            }
        }
        // prefetch next Q
#pragma unroll
        for (int t = 0; t < 2; ++t)
#pragma unroll
            for (int ks = 0; ks < 2; ++ks)
                aQ[t][ks] = *(const uint4*)(qk + ((size_t)b * NPIX + inext + (tiB + t) * 16 + col) * 128 + ks * 32 + quad * 8);

        __syncthreads();   // St[p] written by all; prev iter's St[p] readers long done

        // ---- phase B: acc += V'[.][64i] . St[p]^T ----
#pragma unroll
        for (int ks = 0; ks < 2; ++ks) {
            short8 sb[4];
#pragma unroll
            for (int tj = 0; tj < 4; ++tj)
                sb[tj] = *(const short8*)&St[p][(wjB * 4 + tj) * 16 + col][ks * 32 + quad * 8];
#pragma unroll
            for (int ot = 0; ot < 4; ++ot)
#pragma unroll
                for (int tj = 0; tj < 4; ++tj)
                    acc[ot][tj] = MFMA16x16(*(const short8*)&aV[ot][ks], sb[tj], acc[ot][tj]);
        }
        // prefetch next V
#pragma unroll
        for (int ot = 0; ot < 4; ++ot)
#pragma unroll
            for (int ks = 0; ks < 2; ++ks)
                aV[ot][ks] = *(const uint4*)(vp + ((size_t)b * CH + wo * 64 + ot * 16 + col) * NPIX + inext + ks * 32 + quad * 8);

        p ^= 1;
    }

    // epilogue: atomic add partial (bias pre-initialized by init_out)
#pragma unroll
    for (int ot = 0; ot < 4; ++ot) {
        int ob = wo * 64 + ot * 16 + quad * 4;
#pragma unroll
        for (int tj = 0; tj < 4; ++tj) {
            int j = j0 + wjB * 64 + tj * 16 + col;
#pragma unroll
            for (int r = 0; r < 4; ++r) {
                int o = ob + r;
                atomicAdd(&out[((size_t)b * CH + o) * NPIX + j], acc[ot][tj][r]);
            }
        }
    }
}

// ---------------------------------------------------------------------------
extern "C" void kernel_launch(void* const* d_in, const int* in_sizes, int n_in,
                              void* d_out, int out_size, void* d_ws, size_t ws_size,
                              hipStream_t stream) {
    const float* x  = (const float*)d_in[0];
    const float* wq = (const float*)d_in[1];
    const float* bq = (const float*)d_in[2];
    const float* wk = (const float*)d_in[3];
    const float* bk = (const float*)d_in[4];
    const float* wv = (const float*)d_in[5];
    const float* bv = (const float*)d_in[6];
    const float* wg = (const float*)d_in[7];
    const float* bg = (const float*)d_in[8];
    float* out = (float*)d_out;

    unsigned short* W_all = (unsigned short*)d_ws;
    float* bias_all = (float*)(W_all + 384 * 256);
    unsigned short* xt = (unsigned short*)(bias_all + 384);
    unsigned short* qk = xt + (size_t)BATCH * NPIX * CH;
    unsigned short* vp = qk + (size_t)BATCH * NPIX * 128;

    prep_kernel<<<dim3(384), dim3(256), 0, stream>>>(wq, bq, wk, bk, wv, bv, wg, W_all, bias_all);
    xpose_kernel<<<dim3(NPIX / 64, CH / 64, BATCH), dim3(256), 0, stream>>>(x, xt);
    qkv_mfma<<<dim3(NPIX / 64, 6, BATCH), dim3(256), 0, stream>>>(xt, W_all, bias_all, qk, vp);
    init_out<<<dim3(8192), dim3(256), 0, stream>>>(bg, out);
    attn_v3<<<dim3(512), dim3(512), 0, stream>>>(qk, vp, out);
}

// Round 5
// 267.751 us; speedup vs baseline: 2.0691x; 2.0691x over previous
//
#include <hip/hip_runtime.h>
#include <math.h>

#define BATCH 8
#define CH    256
#define NPIX  4096
#define CKDIM 64

typedef __attribute__((ext_vector_type(8))) short short8;   // 8 bf16 (4 VGPRs)
typedef __attribute__((ext_vector_type(4))) float f32x4;    // MFMA accumulator

#define MFMA16x16(a, b, c) __builtin_amdgcn_mfma_f32_16x16x32_bf16((a), (b), (c), 0, 0, 0)

__device__ __forceinline__ unsigned short f2bf(float f) {
    union { float f; unsigned int u; } v; v.f = f;
    unsigned int u = v.u;
    u += 0x7fffu + ((u >> 16) & 1u);      // round-to-nearest-even
    return (unsigned short)(u >> 16);
}

// ---------------------------------------------------------------------------
// Kernel P: build W_all[384][256] bf16 (rows: 0-63 wq, 64-127 wk, 128-383 wg@wv)
// and bias_all[384] fp32. grid 384 x 256 threads.
// ---------------------------------------------------------------------------
__global__ void prep_kernel(const float* __restrict__ wq, const float* __restrict__ bq,
                            const float* __restrict__ wk, const float* __restrict__ bk,
                            const float* __restrict__ wv, const float* __restrict__ bv,
                            const float* __restrict__ wg,
                            unsigned short* __restrict__ W_all, float* __restrict__ bias_all) {
    int o = blockIdx.x;
    int c = threadIdx.x;
    if (o < 64) {
        W_all[o * CH + c] = f2bf(wq[o * CH + c]);
        if (c == 0) bias_all[o] = bq[o];
    } else if (o < 128) {
        int oo = o - 64;
        W_all[o * CH + c] = f2bf(wk[oo * CH + c]);
        if (c == 0) bias_all[o] = bk[oo];
    } else {
        int oo = o - 128;
        float acc = 0.f;
        for (int m = 0; m < CH; ++m)
            acc += wg[oo * CH + m] * wv[m * CH + c];
        W_all[o * CH + c] = f2bf(acc);
        if (c == 0) {
            float b = 0.f;
            for (int m = 0; m < CH; ++m) b += wg[oo * CH + m] * bv[m];
            bias_all[o] = b;
        }
    }
}

// ---------------------------------------------------------------------------
// Kernel T: transpose+convert x[b][c][n] fp32 -> xt[b][n][c] bf16.
// 64x64 tiles, 256 threads. LDS stride 65 (<=2-way banks). grid (64, 4, 8).
// ---------------------------------------------------------------------------
__global__ void xpose_kernel(const float* __restrict__ x, unsigned short* __restrict__ xt) {
    __shared__ float Tl[64][65];   // [n][c]
    int n0 = blockIdx.x * 64;
    int c0 = blockIdx.y * 64;
    int b  = blockIdx.z;
    int tid = threadIdx.x;

#pragma unroll
    for (int r = 0; r < 4; ++r) {
        int f  = r * 256 + tid;
        int c  = f >> 4;
        int n4 = f & 15;
        float4 v = *(const float4*)(x + ((size_t)b * CH + c0 + c) * NPIX + n0 + n4 * 4);
        Tl[n4 * 4 + 0][c] = v.x;
        Tl[n4 * 4 + 1][c] = v.y;
        Tl[n4 * 4 + 2][c] = v.z;
        Tl[n4 * 4 + 3][c] = v.w;
    }
    __syncthreads();
#pragma unroll
    for (int r = 0; r < 2; ++r) {
        int f    = r * 256 + tid;
        int nrow = f >> 3;
        int c8   = f & 7;
        unsigned int pk[4];
#pragma unroll
        for (int p = 0; p < 4; ++p) {
            unsigned int lo = f2bf(Tl[nrow][c8 * 8 + p * 2 + 0]);
            unsigned int hi = f2bf(Tl[nrow][c8 * 8 + p * 2 + 1]);
            pk[p] = lo | (hi << 16);
        }
        *(uint4*)(xt + ((size_t)b * NPIX + n0 + nrow) * CH + c0 + c8 * 8) = *(uint4*)pk;
    }
}

// ---------------------------------------------------------------------------
// Kernel G: qkv GEMM. Stage 64n x 256ch xt tile in LDS once; loop 6 o-groups.
// y[o][n] = sum_c W_all[o][c] xt[n][c] + bias. o<128 -> qk[b][n][128];
// o>=128 -> vp[b][o-128][n]. grid (64, 8), 256 threads (4 waves).
// ---------------------------------------------------------------------------
__global__ void qkv_mfma(const unsigned short* __restrict__ xt,
                         const unsigned short* __restrict__ W_all,
                         const float* __restrict__ bias_all,
                         unsigned short* __restrict__ qk, unsigned short* __restrict__ vp) {
    __shared__ __align__(16) unsigned short Xl[64][264];   // 33 KB, stride 264 (~conflict-min)

    int n0   = blockIdx.x * 64;
    int b    = blockIdx.y;
    int tid  = threadIdx.x;
    int lane = tid & 63;
    int w    = tid >> 6;
    int col  = lane & 15;
    int quad = lane >> 4;

    // stage xt tile: 64 rows x 256 ch (8 uint4/thread, coalesced)
#pragma unroll
    for (int r = 0; r < 8; ++r) {
        int f   = r * 256 + tid;
        int row = f >> 5;            // 32 uint4 per row
        int c8  = f & 31;
        *(uint4*)&Xl[row][c8 * 8] = *(const uint4*)(xt + ((size_t)b * NPIX + n0 + row) * CH + c8 * 8);
    }
    __syncthreads();

#pragma unroll
    for (int og = 0; og < 6; ++og) {
        int o0 = og * 64;
        const unsigned short* Arow = W_all + (size_t)(o0 + w * 16 + col) * CH + quad * 8;

        f32x4 acc[4];
#pragma unroll
        for (int t = 0; t < 4; ++t) acc[t] = (f32x4){0.f, 0.f, 0.f, 0.f};

#pragma unroll
        for (int kc = 0; kc < 8; ++kc) {
            short8 a = *(const short8*)(Arow + kc * 32);   // L2-hot (196 KB total W)
#pragma unroll
            for (int nt = 0; nt < 4; ++nt) {
                short8 bb = *(const short8*)&Xl[nt * 16 + col][kc * 32 + quad * 8];
                acc[nt] = MFMA16x16(a, bb, acc[nt]);
            }
        }

        float4 bias = *(const float4*)(bias_all + o0 + w * 16 + quad * 4);
        float bs[4] = {bias.x, bias.y, bias.z, bias.w};

        if (og < 2) {
            // q/k: transposed store qk[b][n][o] (uint2 per tile)
#pragma unroll
            for (int nt = 0; nt < 4; ++nt) {
                int n = n0 + nt * 16 + col;
                unsigned int pk[2];
#pragma unroll
                for (int p = 0; p < 2; ++p) {
                    unsigned int lo = f2bf(acc[nt][p * 2 + 0] + bs[p * 2 + 0]);
                    unsigned int hi = f2bf(acc[nt][p * 2 + 1] + bs[p * 2 + 1]);
                    pk[p] = lo | (hi << 16);
                }
                *(uint2*)(qk + ((size_t)b * NPIX + n) * 128 + o0 + w * 16 + quad * 4) = *(uint2*)pk;
            }
        } else {
#pragma unroll
            for (int nt = 0; nt < 4; ++nt) {
                int n = n0 + nt * 16 + col;
#pragma unroll
                for (int r = 0; r < 4; ++r) {
                    int oo = o0 - 128 + w * 16 + quad * 4 + r;
                    vp[((size_t)b * CH + oo) * NPIX + n] = f2bf(acc[nt][r] + bs[r]);
                }
            }
        }
    }
}

// ---------------------------------------------------------------------------
// Kernel A: attention v4. j-tile 64, i-tile 64, 8 waves, LDS-staged Q/V,
// K-frags iteration-invariant in registers. No atomics: full i-range, direct
// float4 stores (phase-B D-layout: o=col, j=rows). grid (64, 8) = 512 blocks,
// LDS 55.3 KB -> 2 blocks/CU.
// ---------------------------------------------------------------------------
#define LPK 72
__global__ __launch_bounds__(512, 4)
void attn_v4(const unsigned short* __restrict__ qk,   // [B][N][128]: q=0..63, k=64..127
             const unsigned short* __restrict__ vp,   // [B][256][N]
             const float* __restrict__ bg, float* __restrict__ out) {
    __shared__ __align__(16) unsigned short Qt[64][LPK];    // [i][ch]  9.2 KB
    __shared__ __align__(16) unsigned short Vl[256][LPK];   // [o][i]  36.9 KB
    __shared__ __align__(16) unsigned short St[64][LPK];    // [j][i]   9.2 KB

    int j0   = blockIdx.x * 64;
    int b    = blockIdx.y;
    int tid  = threadIdx.x;
    int lane = tid & 63;
    int w    = tid >> 6;
    int col  = lane & 15;
    int quad = lane >> 4;

    int tjA = w & 3;              // phase-A j-tile (this wave's K column block)
    int tiP = (w >> 2) * 2;       // phase-A i-tile pair

    // iteration-invariant K fragments (global, once; B-operand: n=j, k=ch)
    short8 bK[2];
#pragma unroll
    for (int ks = 0; ks < 2; ++ks)
        bK[ks] = *(const short8*)(qk + ((size_t)b * NPIX + j0 + tjA * 16 + col) * 128 + 64 + ks * 32 + quad * 8);

    f32x4 acc[2][4];   // [o-tile][j-tile]; D: col=o, rows=j
#pragma unroll
    for (int ot = 0; ot < 2; ++ot)
#pragma unroll
        for (int tj = 0; tj < 4; ++tj) acc[ot][tj] = (f32x4){0.f, 0.f, 0.f, 0.f};

    for (int i0 = 0; i0 < NPIX; i0 += 64) {
        __syncthreads();   // prev iter's phase-B readers done before re-stage

        // stage Q tile 64x64 (1 uint4/thread) + V tile 256x64 (4 uint4/thread)
        {
            int row = tid >> 3, q8 = tid & 7;
            *(uint4*)&Qt[row][q8 * 8] =
                *(const uint4*)(qk + ((size_t)b * NPIX + i0 + row) * 128 + q8 * 8);
        }
#pragma unroll
        for (int r = 0; r < 4; ++r) {
            int f = r * 512 + tid;
            int row = f >> 3, q8 = f & 7;
            *(uint4*)&Vl[row][q8 * 8] =
                *(const uint4*)(vp + ((size_t)b * CH + row) * NPIX + i0 + q8 * 8);
        }
        __syncthreads();

        // ---- phase A: S[64x64] = Q.K^T, elu/N -> St[j][i] bf16 ----
#pragma unroll
        for (int t = 0; t < 2; ++t) {
            int ti = tiP + t;
            short8 a0 = *(const short8*)&Qt[ti * 16 + col][quad * 8];
            short8 a1 = *(const short8*)&Qt[ti * 16 + col][32 + quad * 8];
            f32x4 s = (f32x4){0.f, 0.f, 0.f, 0.f};
            s = MFMA16x16(a0, bK[0], s);
            s = MFMA16x16(a1, bK[1], s);
            unsigned int pk[2];
#pragma unroll
            for (int p = 0; p < 2; ++p) {
                float e0 = s[p * 2 + 0];
                float e1 = s[p * 2 + 1];
                e0 = (e0 > 0.f) ? e0 : (__expf(e0) - 1.f);
                e1 = (e1 > 0.f) ? e1 : (__expf(e1) - 1.f);
                e0 *= (1.f / (float)NPIX);
                e1 *= (1.f / (float)NPIX);
                pk[p] = (unsigned int)f2bf(e0) | ((unsigned int)f2bf(e1) << 16);
            }
            // D of phase A: col=j, rows=4 consecutive i -> St[j][i] uint2
            *(uint2*)&St[tjA * 16 + col][ti * 16 + quad * 4] = *(uint2*)pk;
        }
        __syncthreads();

        // ---- phase B: acc[o][j] += S(A: m=j,k=i) x V(B: n=o,k=i) ----
#pragma unroll
        for (int ks = 0; ks < 2; ++ks) {
            short8 sb[4];
#pragma unroll
            for (int tj = 0; tj < 4; ++tj)
                sb[tj] = *(const short8*)&St[tj * 16 + col][ks * 32 + quad * 8];
#pragma unroll
            for (int ot = 0; ot < 2; ++ot) {
                short8 bv = *(const short8*)&Vl[(w * 2 + ot) * 16 + col][ks * 32 + quad * 8];
#pragma unroll
                for (int tj = 0; tj < 4; ++tj)
                    acc[ot][tj] = MFMA16x16(sb[tj], bv, acc[ot][tj]);
            }
        }
    }

    // epilogue: D col=o, rows=4 consecutive j -> float4 stores
#pragma unroll
    for (int ot = 0; ot < 2; ++ot) {
        int o = (w * 2 + ot) * 16 + col;
        float bgv = bg[o];
#pragma unroll
        for (int tj = 0; tj < 4; ++tj) {
            int j = j0 + tj * 16 + quad * 4;
            float4 st;
            st.x = acc[ot][tj][0] + bgv;
            st.y = acc[ot][tj][1] + bgv;
            st.z = acc[ot][tj][2] + bgv;
            st.w = acc[ot][tj][3] + bgv;
            *(float4*)&out[((size_t)b * CH + o) * NPIX + j] = st;
        }
    }
}

// ---------------------------------------------------------------------------
extern "C" void kernel_launch(void* const* d_in, const int* in_sizes, int n_in,
                              void* d_out, int out_size, void* d_ws, size_t ws_size,
                              hipStream_t stream) {
    const float* x  = (const float*)d_in[0];
    const float* wq = (const float*)d_in[1];
    const float* bq = (const float*)d_in[2];
    const float* wk = (const float*)d_in[3];
    const float* bk = (const float*)d_in[4];
    const float* wv = (const float*)d_in[5];
    const float* bv = (const float*)d_in[6];
    const float* wg = (const float*)d_in[7];
    const float* bg = (const float*)d_in[8];
    float* out = (float*)d_out;

    unsigned short* W_all = (unsigned short*)d_ws;
    float* bias_all = (float*)(W_all + 384 * 256);
    unsigned short* xt = (unsigned short*)(bias_all + 384);
    unsigned short* qk = xt + (size_t)BATCH * NPIX * CH;
    unsigned short* vp = qk + (size_t)BATCH * NPIX * 128;

    prep_kernel<<<dim3(384), dim3(256), 0, stream>>>(wq, bq, wk, bk, wv, bv, wg, W_all, bias_all);
    xpose_kernel<<<dim3(NPIX / 64, CH / 64, BATCH), dim3(256), 0, stream>>>(x, xt);
    qkv_mfma<<<dim3(NPIX / 64, BATCH), dim3(256), 0, stream>>>(xt, W_all, bias_all, qk, vp);
    attn_v4<<<dim3(NPIX / 64, BATCH), dim3(512), 0, stream>>>(qk, vp, bg, out);
}